// Round 13
// baseline (8183.198 us; speedup 1.0000x reference)
//
#include <hip/hip_runtime.h>
#include <math.h>

// Problem constants
#define NB 1024      // batch
#define NH 512       // hidden
#define NT 256       // time steps
#define NCD 2        // per-step output dims

typedef unsigned short u16;
typedef __bf16 bf16x8 __attribute__((ext_vector_type(8)));
typedef float  f32x4  __attribute__((ext_vector_type(4)));

#define MFMA_BF16 __builtin_amdgcn_mfma_f32_16x16x32_bf16

__device__ __forceinline__ float sigf(float x) { return 1.0f / (1.0f + expf(-x)); }
__device__ __forceinline__ float b2f(u16 u) {
    union { unsigned i; float f; } v; v.i = ((unsigned)u) << 16; return v.f;
}
__device__ __forceinline__ u16 f2b(float f) {   // RTNE
    union { float f; unsigned i; } v; v.f = f;
    unsigned r = v.i + 0x7fffu + ((v.i >> 16) & 1u);
    return (u16)(r >> 16);
}

// async 16B global -> LDS (direct-to-shared DMA); lane L lands at base+L*16.
__device__ __forceinline__ void async_cp16(const void* gptr, void* lptr) {
    __builtin_amdgcn_global_load_lds(
        (const __attribute__((address_space(1))) unsigned int*)gptr,
        (__attribute__((address_space(3))) unsigned int*)lptr,
        16, 0, 0);
}

// ---------------------------------------------------------------------------
// weight conversion fp32 -> bf16 (three 2048x512 LSTM weights)
// ---------------------------------------------------------------------------
__global__ __launch_bounds__(256) void convert3(
    const float* __restrict__ a, const float* __restrict__ b,
    const float* __restrict__ c,
    u16* __restrict__ oa, u16* __restrict__ ob, u16* __restrict__ oc)
{
    const int i = blockIdx.x * 256 + threadIdx.x;   // < 2048*512
    oa[i] = f2b(a[i]); ob[i] = f2b(b[i]); oc[i] = f2b(c[i]);
}

// Wo1 (256x512) fp32 -> bf16, SAME row-major [n][k] layout (B-operand rows)
__global__ __launch_bounds__(256) void convw1(
    const float* __restrict__ a, u16* __restrict__ o)
{
    const int i = blockIdx.x * 256 + threadIdx.x;   // < 256*512
    o[i] = f2b(a[i]);
}

__global__ __launch_bounds__(256) void bsum_k(
    const float* __restrict__ bi1, const float* __restrict__ bh1,
    const float* __restrict__ bi2, const float* __restrict__ bh2,
    float* __restrict__ o1, float* __restrict__ o2)
{
    const int i = blockIdx.x * 256 + threadIdx.x;   // < 2048
    o1[i] = bi1[i] + bh1[i];
    o2[i] = bi2[i] + bh2[i];
}

// ---------------------------------------------------------------------------
// init: [h0 | c0] = z @ W_proj^T + b_proj ; h0 (bf16) -> h1,h2 ; c0 (f32)
// ---------------------------------------------------------------------------
__global__ __launch_bounds__(256) void init_kernel(
    const float* __restrict__ zp, const float* __restrict__ zs,
    const float* __restrict__ zst, const float* __restrict__ Wp,
    const float* __restrict__ bp,
    u16* __restrict__ h1, float* __restrict__ c1,
    u16* __restrict__ h2, float* __restrict__ c2)
{
    __shared__ float z[4][256];
    const int tid = threadIdx.x;
    const int b0  = blockIdx.x * 4;
    for (int i = tid; i < 4 * 256; i += 256) {
        const int bb = i >> 8, k = i & 255;
        float v;
        if (k < 64)       v = zp [(b0 + bb) * 64  + k];
        else if (k < 128) v = zs [(b0 + bb) * 64  + (k - 64)];
        else              v = zst[(b0 + bb) * 128 + (k - 128)];
        z[bb][k] = v;
    }
    __syncthreads();
    for (int rt = 0; rt < 4; ++rt) {
        const int r = rt * 256 + tid;          // 0..1023
        const float bias = bp[r];
        float a0 = bias, a1 = bias, a2 = bias, a3 = bias;
        for (int k = 0; k < 256; ++k) {
            const float w = Wp[r * 256 + k];
            a0 += z[0][k] * w; a1 += z[1][k] * w;
            a2 += z[2][k] * w; a3 += z[3][k] * w;
        }
        const float acc[4] = {a0, a1, a2, a3};
        for (int bb = 0; bb < 4; ++bb) {
            const int b = b0 + bb;
            if (r < NH) {
                h1[b * NH + r] = f2b(acc[bb]);
                h2[b * NH + r] = f2b(acc[bb]);
            } else {
                c1[b * NH + r - NH] = acc[bb];
                c2[b * NH + r - NH] = acc[bb];
            }
        }
    }
}

// ---------------------------------------------------------------------------
// FUSED: out(t-1) + lstm1(t), ZERO inter-block communication (R12-verified
// structure).  NEW in R13: phaseA gets the same 3-buffer depth-2 vmcnt
// pipeline as phaseB -- K-macro 32, 3 x 18KB buffers [0,55296), red @55296.
// K-accumulation order unchanged -> bit-identical math vs R12.
// phaseB: lstm1 K-loop, R9-verified 3-buffer depth-2 pipeline (buffers
// 0/20480/40960; red region is dead before buf2's first phaseB write).
// ---------------------------------------------------------------------------
__global__ __launch_bounds__(512, 4) void fused_out_lstm1(
    const u16* __restrict__ h2prev,     // null at t=0 -> skip phaseA (x=0)
    const u16* __restrict__ A0,         // h1c
    const u16* __restrict__ W0,         // Whh1 bf16
    const float* __restrict__ bsum,     // bs1
    const float* __restrict__ Wx,       // Wih1 fp32
    const u16* __restrict__ W1b,        // Wo1 bf16 [256][512]
    const float* __restrict__ bo1, const float* __restrict__ Wo2,
    const float* __restrict__ bo2, float* __restrict__ outp,
    float* __restrict__ c, u16* __restrict__ hnext,
    const int t, const int do_lstm)
{
    __shared__ __align__(16) char smem[61440];
    float* eg  = (float*)smem;                   // lstm epilogue alias
    float* red = (float*)(smem + 55296);         // phaseA: [32 m][8 wv][2 cc]

    const int tid  = threadIdx.x;
    const int lane = tid & 63;
    const int wv   = tid >> 6;          // 0..7
    const int g    = wv & 3;            // gate (phaseB)
    const int mh   = wv >> 2;           // batch half (phaseB)
    const int l15  = lane & 15;
    const int q    = lane >> 4;         // 0..3
    const int bx   = blockIdx.x;
    const int ut   = (bx & 7) * 2 + ((bx >> 3) & 1);  // 0..15
    const int grp  = bx >> 4;                          // 0..31
    const int b0   = grp * 32;
    const int u0   = ut * 32;

    // lstm staging descriptors (R9). W: 2 chunks/wave; A: waves 0..3.
    int goffW0, goffW1, goffA = 0;
    {
        const int c0 = (wv * 2) * 64 + lane;        // 0..1023
        const int w0r = c0 >> 3;                    // g*32+uu
        goffW0 = ((w0r >> 5) * NH + u0 + (w0r & 31)) * NH + (((c0 & 7) ^ (w0r & 7)) * 8);
        const int c1i = (wv * 2 + 1) * 64 + lane;
        const int w1r = c1i >> 3;
        goffW1 = ((w1r >> 5) * NH + u0 + (w1r & 31)) * NH + (((c1i & 7) ^ (w1r & 7)) * 8);
        if (wv < 4) {
            const int ca = wv * 64 + lane;          // 0..255
            const int ar = ca >> 3;                 // batch row 0..31
            goffA = (b0 + ar) * NH + (((ca & 7) ^ (ar & 7)) * 8);
        }
    }
    // phaseA staging descriptors (K-macro 32):
    // Bo: 256 rows x 4 chunks = 1024 chunks -> 2 issues/wave;
    // A:  32 rows x 4 chunks = 128 chunks -> waves 0,1 one issue each.
    int goffO[2], goffA2 = 0;
#pragma unroll
    for (int i = 0; i < 2; ++i) {
        const int cidx = (wv * 2 + i) * 64 + lane;   // 0..1023
        const int row  = cidx >> 2;                  // n 0..255
        const int j    = cidx & 3;
        goffO[i] = row * NH + ((j ^ (row & 3)) * 8);
    }
    if (wv < 2) {
        const int ca  = wv * 64 + lane;              // 0..127
        const int row = ca >> 2;                     // 0..31
        const int j   = ca & 3;
        goffA2 = (b0 + row) * NH + ((j ^ (row & 3)) * 8);
    }

    float r_x[4] = {0.f, 0.f, 0.f, 0.f};   // [jj*2+cc], y for rows bq*2+jj

    // ---------------- phase A: out(t-1), 3-buffer depth-2 pipeline ---------
    if (h2prev) {
        f32x4 acc_o[2][2];
#pragma unroll
        for (int mi = 0; mi < 2; ++mi)
#pragma unroll
            for (int ni = 0; ni < 2; ++ni)
                acc_o[mi][ni] = (f32x4){0.f, 0.f, 0.f, 0.f};

        auto issueA = [&](int kk, int bi) {
            const int k0 = kk * 32;
            char* base = smem + bi * 18432;          // Bo 16KB | A 2KB
            async_cp16((const void*)(W1b + goffO[0] + k0),
                       (void*)(base + (wv * 2) * 1024));
            async_cp16((const void*)(W1b + goffO[1] + k0),
                       (void*)(base + (wv * 2 + 1) * 1024));
            if (wv < 2)
                async_cp16((const void*)(h2prev + goffA2 + k0),
                           (void*)(base + 16384 + (wv << 10)));
        };

        issueA(0, 0); issueA(1, 1);
        int ai = 0;
        for (int kk = 0; kk < 16; ++kk) {
            if (kk + 1 < 16) {
                if (wv < 2) asm volatile("s_waitcnt vmcnt(3)" ::: "memory");
                else        asm volatile("s_waitcnt vmcnt(2)" ::: "memory");
            } else {
                asm volatile("s_waitcnt vmcnt(0)" ::: "memory");
            }
            __builtin_amdgcn_s_barrier();
            if (kk + 2 < 16) {
                int bi = ai + 2; if (bi >= 3) bi -= 3;
                issueA(kk + 2, bi);
            }
            const char* bB  = smem + ai * 18432;
            const char* bA2 = bB + 16384;
            bf16x8 bfr[2], av[2];
#pragma unroll
            for (int ni = 0; ni < 2; ++ni) {
                const int wrow = wv * 32 + ni * 16 + l15;    // n
                const int j = q ^ (wrow & 3);
                bfr[ni] = *(const bf16x8*)(bB + wrow * 64 + j * 16);
            }
#pragma unroll
            for (int mi = 0; mi < 2; ++mi) {
                const int row = mi * 16 + l15;               // m
                const int j = q ^ (row & 3);
                av[mi] = *(const bf16x8*)(bA2 + row * 64 + j * 16);
            }
#pragma unroll
            for (int mi = 0; mi < 2; ++mi)
#pragma unroll
                for (int ni = 0; ni < 2; ++ni)
                    acc_o[mi][ni] = MFMA_BF16(av[mi], bfr[ni], acc_o[mi][ni], 0, 0, 0);
            ++ai; if (ai == 3) ai = 0;
        }

        // epilogue: relu(pre1+bo1) * Wo2, reduce over n  (R12-identical)
        float bo1n[2], w20[2], w21[2];
#pragma unroll
        for (int ni = 0; ni < 2; ++ni) {
            const int n = wv * 32 + ni * 16 + l15;
            bo1n[ni] = bo1[n]; w20[ni] = Wo2[n]; w21[ni] = Wo2[256 + n];
        }
        float pa[2][4], pb[2][4];
#pragma unroll
        for (int mi = 0; mi < 2; ++mi)
#pragma unroll
            for (int r = 0; r < 4; ++r) {
                const float s0 = fmaxf(acc_o[mi][0][r] + bo1n[0], 0.f);
                const float s1 = fmaxf(acc_o[mi][1][r] + bo1n[1], 0.f);
                pa[mi][r] = s0 * w20[0] + s1 * w20[1];
                pb[mi][r] = s0 * w21[0] + s1 * w21[1];
            }
#pragma unroll
        for (int off = 1; off < 16; off <<= 1)
#pragma unroll
            for (int mi = 0; mi < 2; ++mi)
#pragma unroll
                for (int r = 0; r < 4; ++r) {
                    pa[mi][r] += __shfl_xor(pa[mi][r], off, 64);
                    pb[mi][r] += __shfl_xor(pb[mi][r], off, 64);
                }
        if (l15 == 0) {
#pragma unroll
            for (int mi = 0; mi < 2; ++mi)
#pragma unroll
                for (int r = 0; r < 4; ++r) {
                    const int m = mi * 16 + q * 4 + r;
                    red[m * 16 + wv * 2 + 0] = pa[mi][r];
                    red[m * 16 + wv * 2 + 1] = pb[mi][r];
                }
        }
        __syncthreads();
        if (ut == 0 && tid < 64) {          // one writer tile per grp
            const int bl = tid >> 1, cc = tid & 1;
            float y = bo2[cc];
#pragma unroll
            for (int w8 = 0; w8 < 8; ++w8) y += red[bl * 16 + w8 * 2 + cc];
            outp[(size_t)(b0 + bl) * (NT * NCD) + (t - 1) * NCD + cc] = y;
        }
        if (do_lstm) {                      // everyone grabs its own rows
            const int bq = tid >> 5;        // 0..15
#pragma unroll
            for (int jj = 0; jj < 2; ++jj)
#pragma unroll
                for (int cc = 0; cc < 2; ++cc) {
                    float y = bo2[cc];
#pragma unroll
                    for (int w8 = 0; w8 < 8; ++w8)
                        y += red[(bq * 2 + jj) * 16 + w8 * 2 + cc];
                    r_x[jj * 2 + cc] = y;
                }
        }
        __syncthreads();                    // red reads done before LDS reuse
    }
    if (!do_lstm) return;                   // final out-only dispatch

    // ---------------- phase B: lstm1 K-loop (R9-verified) ----------------
    auto issue = [&](int m, int bi) {
        const int k0 = (m & 7) * 64;
        char* base = smem + bi * 20480;     // As 4KB | Ws 16KB
        async_cp16((const void*)(W0 + goffW0 + k0),
                   (void*)(base + 4096 + (wv * 2) * 1024));
        async_cp16((const void*)(W0 + goffW1 + k0),
                   (void*)(base + 4096 + (wv * 2 + 1) * 1024));
        if (wv < 4)
            async_cp16((const void*)(A0 + goffA + k0),
                       (void*)(base + wv * 1024));
    };

    f32x4 acc[2];
    acc[0] = (f32x4){0.f, 0.f, 0.f, 0.f};
    acc[1] = (f32x4){0.f, 0.f, 0.f, 0.f};
    const int M = 8;
    issue(0, 0); issue(1, 1);
    int ci = 0;
    for (int m = 0; m < M; ++m) {
        if (m + 1 < M) {
            if (wv < 4) asm volatile("s_waitcnt vmcnt(3)" ::: "memory");
            else        asm volatile("s_waitcnt vmcnt(2)" ::: "memory");
        } else {
            asm volatile("s_waitcnt vmcnt(0)" ::: "memory");
        }
        __builtin_amdgcn_s_barrier();
        if (m + 2 < M) {
            int bi = ci + 2; if (bi >= 3) bi -= 3;
            issue(m + 2, bi);
        }
        const char* bA = smem + ci * 20480;
        const char* bW = bA + 4096;
#pragma unroll
        for (int khi = 0; khi < 2; ++khi) {
            bf16x8 bfr[2];
#pragma unroll
            for (int ni = 0; ni < 2; ++ni) {
                const int wrow = g * 32 + ni * 16 + l15;
                const int j = (khi * 4 + q) ^ (wrow & 7);
                bfr[ni] = *(const bf16x8*)(bW + wrow * 128 + j * 16);
            }
            const int row = mh * 16 + l15;
            const int j = (khi * 4 + q) ^ (row & 7);
            const bf16x8 av = *(const bf16x8*)(bA + row * 128 + j * 16);
            acc[0] = MFMA_BF16(av, bfr[0], acc[0], 0, 0, 0);
            acc[1] = MFMA_BF16(av, bfr[1], acc[1], 0, 0, 0);
        }
        ++ci; if (ci == 3) ci = 0;
    }

    __syncthreads();
    // eg[g][b_local][u_local], stride 33 ; C/D: row=q*4+r, col=l15 [m89]
#pragma unroll
    for (int ni = 0; ni < 2; ++ni)
#pragma unroll
        for (int r = 0; r < 4; ++r)
            eg[(g * 32 + mh * 16 + q * 4 + r) * 33 + ni * 16 + l15] = acc[ni][r];
    __syncthreads();

    // fused pointwise cell update: thread -> unit u, 2 batch rows; x from r_x
    const int u  = tid & 31;
    const int bq = tid >> 5;            // 0..15
    const int ug = u0 + u;
    float bs[4], wx0[4], wx1[4];
#pragma unroll
    for (int g4 = 0; g4 < 4; ++g4) bs[g4] = bsum[g4 * NH + ug];
#pragma unroll
    for (int g4 = 0; g4 < 4; ++g4) {
        wx0[g4] = Wx[(g4 * NH + ug) * 2 + 0];
        wx1[g4] = Wx[(g4 * NH + ug) * 2 + 1];
    }
#pragma unroll
    for (int jj = 0; jj < 2; ++jj) {
        const int bl = bq * 2 + jj;
        const int b  = b0 + bl;
        float gv[4];
#pragma unroll
        for (int g4 = 0; g4 < 4; ++g4) gv[g4] = eg[(g4 * 32 + bl) * 33 + u] + bs[g4];
        const float x0 = r_x[jj * 2 + 0];
        const float x1 = r_x[jj * 2 + 1];
#pragma unroll
        for (int g4 = 0; g4 < 4; ++g4) gv[g4] += x0 * wx0[g4] + x1 * wx1[g4];
        const float iv = sigf(gv[0]);
        const float fv = sigf(gv[1]);
        const float gg = tanhf(gv[2]);
        const float ov = sigf(gv[3]);
        const size_t idx = (size_t)b * NH + ug;
        const float cn = fv * c[idx] + iv * gg;
        c[idx] = cn;
        hnext[idx] = f2b(ov * tanhf(cn));
    }
}

// ---------------------------------------------------------------------------
// LSTM2: R9-verified kernel, unchanged (npass=2, no x-term).
// ---------------------------------------------------------------------------
__global__ __launch_bounds__(512, 4) void lstm_mfma32(
    const u16* __restrict__ A0, const u16* __restrict__ W0,
    const u16* __restrict__ A1, const u16* __restrict__ W1,
    const float* __restrict__ bsum,
    float* __restrict__ c, u16* __restrict__ hnext,
    const int npass)
{
    __shared__ __align__(16) char smem[61440];
    float* eg = (float*)smem;

    const int tid  = threadIdx.x;
    const int lane = tid & 63;
    const int wv   = tid >> 6;
    const int g    = wv & 3;
    const int mh   = wv >> 2;
    const int l15  = lane & 15;
    const int q    = lane >> 4;
    const int bx   = blockIdx.x;
    const int ut   = (bx & 7) * 2 + ((bx >> 3) & 1);
    const int grp  = bx >> 4;
    const int b0   = grp * 32;
    const int u0   = ut * 32;

    int goffW0, goffW1, goffA = 0;
    {
        const int c0 = (wv * 2) * 64 + lane;
        const int w0r = c0 >> 3;
        goffW0 = ((w0r >> 5) * NH + u0 + (w0r & 31)) * NH + (((c0 & 7) ^ (w0r & 7)) * 8);
        const int c1i = (wv * 2 + 1) * 64 + lane;
        const int w1r = c1i >> 3;
        goffW1 = ((w1r >> 5) * NH + u0 + (w1r & 31)) * NH + (((c1i & 7) ^ (w1r & 7)) * 8);
        if (wv < 4) {
            const int ca = wv * 64 + lane;
            const int ar = ca >> 3;
            goffA = (b0 + ar) * NH + (((ca & 7) ^ (ar & 7)) * 8);
        }
    }

    f32x4 acc[2];
    acc[0] = (f32x4){0.f, 0.f, 0.f, 0.f};
    acc[1] = (f32x4){0.f, 0.f, 0.f, 0.f};

    const int M = npass * 8;

    auto issue = [&](int m, int bi) {
        const u16* __restrict__ Ap = (m < 8) ? A0 : A1;
        const u16* __restrict__ Wp = (m < 8) ? W0 : W1;
        const int k0 = (m & 7) * 64;
        char* base = smem + bi * 20480;
        async_cp16((const void*)(Wp + goffW0 + k0),
                   (void*)(base + 4096 + (wv * 2) * 1024));
        async_cp16((const void*)(Wp + goffW1 + k0),
                   (void*)(base + 4096 + (wv * 2 + 1) * 1024));
        if (wv < 4)
            async_cp16((const void*)(Ap + goffA + k0),
                       (void*)(base + wv * 1024));
    };

    issue(0, 0);
    if (M > 1) issue(1, 1);
    int ci = 0;
    for (int m = 0; m < M; ++m) {
        if (m + 1 < M) {
            if (wv < 4) asm volatile("s_waitcnt vmcnt(3)" ::: "memory");
            else        asm volatile("s_waitcnt vmcnt(2)" ::: "memory");
        } else {
            asm volatile("s_waitcnt vmcnt(0)" ::: "memory");
        }
        __builtin_amdgcn_s_barrier();
        if (m + 2 < M) {
            int bi = ci + 2; if (bi >= 3) bi -= 3;
            issue(m + 2, bi);
        }
        const char* bA = smem + ci * 20480;
        const char* bW = bA + 4096;
#pragma unroll
        for (int khi = 0; khi < 2; ++khi) {
            bf16x8 bfr[2];
#pragma unroll
            for (int ni = 0; ni < 2; ++ni) {
                const int wrow = g * 32 + ni * 16 + l15;
                const int j = (khi * 4 + q) ^ (wrow & 7);
                bfr[ni] = *(const bf16x8*)(bW + wrow * 128 + j * 16);
            }
            const int row = mh * 16 + l15;
            const int j = (khi * 4 + q) ^ (row & 7);
            const bf16x8 av = *(const bf16x8*)(bA + row * 128 + j * 16);
            acc[0] = MFMA_BF16(av, bfr[0], acc[0], 0, 0, 0);
            acc[1] = MFMA_BF16(av, bfr[1], acc[1], 0, 0, 0);
        }
        ++ci; if (ci == 3) ci = 0;
    }

    __syncthreads();
#pragma unroll
    for (int ni = 0; ni < 2; ++ni)
#pragma unroll
        for (int r = 0; r < 4; ++r)
            eg[(g * 32 + mh * 16 + q * 4 + r) * 33 + ni * 16 + l15] = acc[ni][r];
    __syncthreads();

    const int u  = tid & 31;
    const int bq = tid >> 5;
    const int ug = u0 + u;
    float bs[4];
#pragma unroll
    for (int g4 = 0; g4 < 4; ++g4) bs[g4] = bsum[g4 * NH + ug];
#pragma unroll
    for (int jj = 0; jj < 2; ++jj) {
        const int bl = bq * 2 + jj;
        const int b  = b0 + bl;
        float gv[4];
#pragma unroll
        for (int g4 = 0; g4 < 4; ++g4) gv[g4] = eg[(g4 * 32 + bl) * 33 + u] + bs[g4];
        const float iv = sigf(gv[0]);
        const float fv = sigf(gv[1]);
        const float gg = tanhf(gv[2]);
        const float ov = sigf(gv[3]);
        const size_t idx = (size_t)b * NH + ug;
        const float cn = fv * c[idx] + iv * gg;
        c[idx] = cn;
        hnext[idx] = f2b(ov * tanhf(cn));
    }
}

// ---------------------------------------------------------------------------
extern "C" void kernel_launch(void* const* d_in, const int* in_sizes, int n_in,
                              void* d_out, int out_size, void* d_ws, size_t ws_size,
                              hipStream_t stream)
{
    const float* zp   = (const float*)d_in[0];
    const float* zsk  = (const float*)d_in[1];
    const float* zst  = (const float*)d_in[2];
    const float* Wp   = (const float*)d_in[3];
    const float* bp   = (const float*)d_in[4];
    const float* Wih1 = (const float*)d_in[5];
    const float* Whh1 = (const float*)d_in[6];
    const float* bih1 = (const float*)d_in[7];
    const float* bhh1 = (const float*)d_in[8];
    const float* Wih2 = (const float*)d_in[9];
    const float* Whh2 = (const float*)d_in[10];
    const float* bih2 = (const float*)d_in[11];
    const float* bhh2 = (const float*)d_in[12];
    const float* Wo1  = (const float*)d_in[13];
    const float* bo1  = (const float*)d_in[14];
    const float* Wo2  = (const float*)d_in[15];
    const float* bo2  = (const float*)d_in[16];

    const size_t BH = (size_t)NB * NH;          // 524288
    u16*   h1a   = (u16*)d_ws;
    u16*   h1b   = h1a + BH;
    u16*   h2a   = h1b + BH;
    u16*   h2b   = h2a + BH;
    float* c1    = (float*)(h2b + BH);
    float* c2    = c1 + BH;
    float* bs1   = c2 + BH;                     // 2048
    float* bs2   = bs1 + 2048;                  // 2048
    u16*   Wo1b  = (u16*)(bs2 + 2048);          // 131072 u16 (row-major bf16)
    u16*   Whh1b = Wo1b + 131072;               // 1048576 each
    u16*   Wih2b = Whh1b + 1048576;
    u16*   Whh2b = Wih2b + 1048576;
    // total ~14.3 MB of d_ws

    convert3<<<(2048 * 512) / 256, 256, 0, stream>>>(Whh1, Wih2, Whh2, Whh1b, Wih2b, Whh2b);
    convw1<<<(256 * 512) / 256, 256, 0, stream>>>(Wo1, Wo1b);
    bsum_k<<<2048 / 256, 256, 0, stream>>>(bih1, bhh1, bih2, bhh2, bs1, bs2);
    init_kernel<<<NB / 4, 256, 0, stream>>>(zp, zsk, zst, Wp, bp, h1a, c1, h2a, c2);

    u16* h1c = h1a; u16* h1n = h1b;
    u16* h2c = h2a; u16* h2n = h2b;
    float* outp = (float*)d_out;
    for (int t = 0; t < NT; ++t) {
        fused_out_lstm1<<<512, 512, 0, stream>>>(
            (t == 0) ? (const u16*)0 : h2c, h1c, Whh1b, bs1, Wih1,
            Wo1b, bo1, Wo2, bo2, outp, c1, h1n, t, 1);
        lstm_mfma32<<<512, 512, 0, stream>>>(h1n, Wih2b, h2c, Whh2b,
                                             bs2, c2, h2n, 2);
        u16* tmp = h1c; h1c = h1n; h1n = tmp;
        tmp = h2c; h2c = h2n; h2n = tmp;
    }
    // final out for t = NT-1 (h2c holds h2(NT-1) after the last swap)
    fused_out_lstm1<<<512, 512, 0, stream>>>(
        h2c, h1c, Whh1b, bs1, Wih1,
        Wo1b, bo1, Wo2, bo2, outp, c1, h1n, NT, 0);
}

// Round 14
// 7453.815 us; speedup vs baseline: 1.0979x; 1.0979x over previous
//
#include <hip/hip_runtime.h>
#include <math.h>

// Problem constants
#define NB 1024      // batch
#define NH 512       // hidden
#define NT 256       // time steps
#define NCD 2        // per-step output dims

typedef unsigned short u16;
typedef __bf16 bf16x8 __attribute__((ext_vector_type(8)));
typedef float  f32x4  __attribute__((ext_vector_type(4)));

#define MFMA_BF16 __builtin_amdgcn_mfma_f32_16x16x32_bf16

__device__ __forceinline__ float sigf(float x) { return 1.0f / (1.0f + expf(-x)); }
__device__ __forceinline__ float b2f(u16 u) {
    union { unsigned i; float f; } v; v.i = ((unsigned)u) << 16; return v.f;
}
__device__ __forceinline__ u16 f2b(float f) {   // RTNE
    union { float f; unsigned i; } v; v.f = f;
    unsigned r = v.i + 0x7fffu + ((v.i >> 16) & 1u);
    return (u16)(r >> 16);
}

// async 16B global -> LDS (direct-to-shared DMA); lane L lands at base+L*16.
__device__ __forceinline__ void async_cp16(const void* gptr, void* lptr) {
    __builtin_amdgcn_global_load_lds(
        (const __attribute__((address_space(1))) unsigned int*)gptr,
        (__attribute__((address_space(3))) unsigned int*)lptr,
        16, 0, 0);
}

// ---------------------------------------------------------------------------
// weight conversion fp32 -> bf16 (three 2048x512 LSTM weights)
// ---------------------------------------------------------------------------
__global__ __launch_bounds__(256) void convert3(
    const float* __restrict__ a, const float* __restrict__ b,
    const float* __restrict__ c,
    u16* __restrict__ oa, u16* __restrict__ ob, u16* __restrict__ oc)
{
    const int i = blockIdx.x * 256 + threadIdx.x;   // < 2048*512
    oa[i] = f2b(a[i]); ob[i] = f2b(b[i]); oc[i] = f2b(c[i]);
}

// Wo1 (256x512) fp32 -> bf16, SAME row-major [n][k] layout (B-operand rows)
__global__ __launch_bounds__(256) void convw1(
    const float* __restrict__ a, u16* __restrict__ o)
{
    const int i = blockIdx.x * 256 + threadIdx.x;   // < 256*512
    o[i] = f2b(a[i]);
}

__global__ __launch_bounds__(256) void bsum_k(
    const float* __restrict__ bi1, const float* __restrict__ bh1,
    const float* __restrict__ bi2, const float* __restrict__ bh2,
    float* __restrict__ o1, float* __restrict__ o2)
{
    const int i = blockIdx.x * 256 + threadIdx.x;   // < 2048
    o1[i] = bi1[i] + bh1[i];
    o2[i] = bi2[i] + bh2[i];
}

// ---------------------------------------------------------------------------
// init: [h0 | c0] = z @ W_proj^T + b_proj ; h0 (bf16) -> h1,h2 ; c0 (f32)
// ---------------------------------------------------------------------------
__global__ __launch_bounds__(256) void init_kernel(
    const float* __restrict__ zp, const float* __restrict__ zs,
    const float* __restrict__ zst, const float* __restrict__ Wp,
    const float* __restrict__ bp,
    u16* __restrict__ h1, float* __restrict__ c1,
    u16* __restrict__ h2, float* __restrict__ c2)
{
    __shared__ float z[4][256];
    const int tid = threadIdx.x;
    const int b0  = blockIdx.x * 4;
    for (int i = tid; i < 4 * 256; i += 256) {
        const int bb = i >> 8, k = i & 255;
        float v;
        if (k < 64)       v = zp [(b0 + bb) * 64  + k];
        else if (k < 128) v = zs [(b0 + bb) * 64  + (k - 64)];
        else              v = zst[(b0 + bb) * 128 + (k - 128)];
        z[bb][k] = v;
    }
    __syncthreads();
    for (int rt = 0; rt < 4; ++rt) {
        const int r = rt * 256 + tid;          // 0..1023
        const float bias = bp[r];
        float a0 = bias, a1 = bias, a2 = bias, a3 = bias;
        for (int k = 0; k < 256; ++k) {
            const float w = Wp[r * 256 + k];
            a0 += z[0][k] * w; a1 += z[1][k] * w;
            a2 += z[2][k] * w; a3 += z[3][k] * w;
        }
        const float acc[4] = {a0, a1, a2, a3};
        for (int bb = 0; bb < 4; ++bb) {
            const int b = b0 + bb;
            if (r < NH) {
                h1[b * NH + r] = f2b(acc[bb]);
                h2[b * NH + r] = f2b(acc[bb]);
            } else {
                c1[b * NH + r - NH] = acc[bb];
                c2[b * NH + r - NH] = acc[bb];
            }
        }
    }
}

// ---------------------------------------------------------------------------
// FUSED: out(t-1) + lstm1(t), ZERO inter-block communication (R12-verified).
// R14 deltas vs R12 (both zero-risk latency hides, math untouched):
//  (1) phaseB macro-0 pre-issued into buf2 [40960,61440) at kernel start --
//      disjoint from phaseA's [0,38912); loads land during phaseA (~4us).
//      phaseB buffer order becomes 2,0,1,2,... (rotation re-derived).
//  (2) epilogue scalars (bsum, Wx, c) prefetched into registers at start;
//      they retire during phaseA / early K-loop (in-order retirement).
// phaseA: R12-exact single-buffer K=64 MFMA GEMM (Bo 32KB@0|A 4KB@32768|
//   red@36864), vmcnt(0) per macro.
// phaseB: R9-verified 3-buffer depth-2 vmcnt pipeline.
// ---------------------------------------------------------------------------
__global__ __launch_bounds__(512, 4) void fused_out_lstm1(
    const u16* __restrict__ h2prev,     // null at t=0 -> skip phaseA (x=0)
    const u16* __restrict__ A0,         // h1c
    const u16* __restrict__ W0,         // Whh1 bf16
    const float* __restrict__ bsum,     // bs1
    const float* __restrict__ Wx,       // Wih1 fp32
    const u16* __restrict__ W1b,        // Wo1 bf16 [256][512]
    const float* __restrict__ bo1, const float* __restrict__ Wo2,
    const float* __restrict__ bo2, float* __restrict__ outp,
    float* __restrict__ c, u16* __restrict__ hnext,
    const int t, const int do_lstm)
{
    __shared__ __align__(16) char smem[61440];   // 3 x (As 4KB | Ws 16KB)
    float* eg  = (float*)smem;                   // lstm epilogue alias
    float* red = (float*)(smem + 36864);         // phaseA: [32 m][8 wv][2 cc]

    const int tid  = threadIdx.x;
    const int lane = tid & 63;
    const int wv   = tid >> 6;          // 0..7
    const int g    = wv & 3;            // gate (phaseB)
    const int mh   = wv >> 2;           // batch half (phaseB)
    const int l15  = lane & 15;
    const int q    = lane >> 4;         // 0..3
    const int bx   = blockIdx.x;
    const int ut   = (bx & 7) * 2 + ((bx >> 3) & 1);  // 0..15
    const int grp  = bx >> 4;                          // 0..31
    const int b0   = grp * 32;
    const int u0   = ut * 32;

    // staging descriptors. lstm W: 2 chunks/wave; A: waves 0..3 (32 rows);
    // phaseA Bo (Wo1): 4 chunks/wave (256 rows x 8 kc = 2048 chunks).
    int goffW0, goffW1, goffA = 0, goffO[4];
    {
        const int c0 = (wv * 2) * 64 + lane;        // 0..1023
        const int w0r = c0 >> 3;                    // g*32+uu
        goffW0 = ((w0r >> 5) * NH + u0 + (w0r & 31)) * NH + (((c0 & 7) ^ (w0r & 7)) * 8);
        const int c1i = (wv * 2 + 1) * 64 + lane;
        const int w1r = c1i >> 3;
        goffW1 = ((w1r >> 5) * NH + u0 + (w1r & 31)) * NH + (((c1i & 7) ^ (w1r & 7)) * 8);
        if (wv < 4) {
            const int ca = wv * 64 + lane;          // 0..255
            const int ar = ca >> 3;                 // batch row 0..31
            goffA = (b0 + ar) * NH + (((ca & 7) ^ (ar & 7)) * 8);
        }
#pragma unroll
        for (int i = 0; i < 4; ++i) {
            const int cidx = (wv * 4 + i) * 64 + lane;   // 0..2047
            const int row  = cidx >> 3;                  // n 0..255
            const int kc   = (cidx & 7) ^ (row & 7);
            goffO[i] = row * NH + kc * 8;
        }
    }

    auto issue = [&](int m, int bi) {            // phaseB staging
        const int k0 = (m & 7) * 64;
        char* base = smem + bi * 20480;          // As 4KB | Ws 16KB
        async_cp16((const void*)(W0 + goffW0 + k0),
                   (void*)(base + 4096 + (wv * 2) * 1024));
        async_cp16((const void*)(W0 + goffW1 + k0),
                   (void*)(base + 4096 + (wv * 2 + 1) * 1024));
        if (wv < 4)
            async_cp16((const void*)(A0 + goffA + k0),
                       (void*)(base + wv * 1024));
    };

    // ---- R14 delta (2): early scalar prefetch (retires during phaseA) ----
    const int u_e  = tid & 31;
    const int bq_e = tid >> 5;          // 0..15
    const int ug_e = u0 + u_e;
    float bs[4], wx0[4], wx1[4], cpre[2];
#pragma unroll
    for (int g4 = 0; g4 < 4; ++g4) bs[g4] = bsum[g4 * NH + ug_e];
#pragma unroll
    for (int g4 = 0; g4 < 4; ++g4) {
        wx0[g4] = Wx[(g4 * NH + ug_e) * 2 + 0];
        wx1[g4] = Wx[(g4 * NH + ug_e) * 2 + 1];
    }
    cpre[0] = c[(size_t)(b0 + bq_e * 2 + 0) * NH + ug_e];
    cpre[1] = c[(size_t)(b0 + bq_e * 2 + 1) * NH + ug_e];

    // ---- R14 delta (1): pre-issue phaseB macro 0 into buf2 ----------------
    if (do_lstm) issue(0, 2);

    float r_x[4] = {0.f, 0.f, 0.f, 0.f};   // [jj*2+cc], y for rows bq*2+jj

    // ---------------- phase A: out(t-1) for this block's 32 rows -----------
    if (h2prev) {
        f32x4 acc_o[2][2];
#pragma unroll
        for (int mi = 0; mi < 2; ++mi)
#pragma unroll
            for (int ni = 0; ni < 2; ++ni)
                acc_o[mi][ni] = (f32x4){0.f, 0.f, 0.f, 0.f};

        for (int kk = 0; kk < 8; ++kk) {
            __syncthreads();                     // prev macro's readers done
            const int k0 = kk * 64;
#pragma unroll
            for (int i = 0; i < 4; ++i)
                async_cp16((const void*)(W1b + goffO[i] + k0),
                           (void*)(smem + ((wv * 4 + i) << 10)));
            if (wv < 4)
                async_cp16((const void*)(h2prev + goffA + k0),
                           (void*)(smem + 32768 + (wv << 10)));
            asm volatile("s_waitcnt vmcnt(0)" ::: "memory");
            __builtin_amdgcn_s_barrier();
#pragma unroll
            for (int kh = 0; kh < 2; ++kh) {
                bf16x8 bfr[2], av[2];
#pragma unroll
                for (int ni = 0; ni < 2; ++ni) {
                    const int wrow = wv * 32 + ni * 16 + l15;   // n
                    const int j = (kh * 4 + q) ^ (wrow & 7);
                    bfr[ni] = *(const bf16x8*)(smem + wrow * 128 + j * 16);
                }
#pragma unroll
                for (int mi = 0; mi < 2; ++mi) {
                    const int row = mi * 16 + l15;              // m
                    const int j = (kh * 4 + q) ^ (row & 7);
                    av[mi] = *(const bf16x8*)(smem + 32768 + row * 128 + j * 16);
                }
#pragma unroll
                for (int mi = 0; mi < 2; ++mi)
#pragma unroll
                    for (int ni = 0; ni < 2; ++ni)
                        acc_o[mi][ni] = MFMA_BF16(av[mi], bfr[ni], acc_o[mi][ni], 0, 0, 0);
            }
        }
        // epilogue: relu(pre1+bo1) * Wo2, reduce over n
        float bo1n[2], w20[2], w21[2];
#pragma unroll
        for (int ni = 0; ni < 2; ++ni) {
            const int n = wv * 32 + ni * 16 + l15;
            bo1n[ni] = bo1[n]; w20[ni] = Wo2[n]; w21[ni] = Wo2[256 + n];
        }
        float pa[2][4], pb[2][4];
#pragma unroll
        for (int mi = 0; mi < 2; ++mi)
#pragma unroll
            for (int r = 0; r < 4; ++r) {
                const float s0 = fmaxf(acc_o[mi][0][r] + bo1n[0], 0.f);
                const float s1 = fmaxf(acc_o[mi][1][r] + bo1n[1], 0.f);
                pa[mi][r] = s0 * w20[0] + s1 * w20[1];
                pb[mi][r] = s0 * w21[0] + s1 * w21[1];
            }
#pragma unroll
        for (int off = 1; off < 16; off <<= 1)
#pragma unroll
            for (int mi = 0; mi < 2; ++mi)
#pragma unroll
                for (int r = 0; r < 4; ++r) {
                    pa[mi][r] += __shfl_xor(pa[mi][r], off, 64);
                    pb[mi][r] += __shfl_xor(pb[mi][r], off, 64);
                }
        if (l15 == 0) {
#pragma unroll
            for (int mi = 0; mi < 2; ++mi)
#pragma unroll
                for (int r = 0; r < 4; ++r) {
                    const int m = mi * 16 + q * 4 + r;
                    red[m * 16 + wv * 2 + 0] = pa[mi][r];
                    red[m * 16 + wv * 2 + 1] = pb[mi][r];
                }
        }
        __syncthreads();
        if (ut == 0 && tid < 64) {          // one writer tile per grp
            const int bl = tid >> 1, cc = tid & 1;
            float y = bo2[cc];
#pragma unroll
            for (int w8 = 0; w8 < 8; ++w8) y += red[bl * 16 + w8 * 2 + cc];
            outp[(size_t)(b0 + bl) * (NT * NCD) + (t - 1) * NCD + cc] = y;
        }
        if (do_lstm) {                      // everyone grabs its own rows
            const int bq = tid >> 5;        // 0..15
#pragma unroll
            for (int jj = 0; jj < 2; ++jj)
#pragma unroll
                for (int cc = 0; cc < 2; ++cc) {
                    float y = bo2[cc];
#pragma unroll
                    for (int w8 = 0; w8 < 8; ++w8)
                        y += red[(bq * 2 + jj) * 16 + w8 * 2 + cc];
                    r_x[jj * 2 + cc] = y;
                }
        }
        __syncthreads();                    // red reads done before LDS reuse
    }
    if (!do_lstm) return;                   // final out-only dispatch

    // ---------------- phase B: lstm1 K-loop (buf order 2,0,1,...) ----------
    f32x4 acc[2];
    acc[0] = (f32x4){0.f, 0.f, 0.f, 0.f};
    acc[1] = (f32x4){0.f, 0.f, 0.f, 0.f};
    const int M = 8;
    issue(1, 0);                            // macro0 already in flight -> buf2
    int ci = 2;
    for (int m = 0; m < M; ++m) {
        if (m + 1 < M) {
            if (wv < 4) asm volatile("s_waitcnt vmcnt(3)" ::: "memory");
            else        asm volatile("s_waitcnt vmcnt(2)" ::: "memory");
        } else {
            asm volatile("s_waitcnt vmcnt(0)" ::: "memory");
        }
        __builtin_amdgcn_s_barrier();
        if (m + 2 < M) {
            int bi = ci + 2; if (bi >= 3) bi -= 3;
            issue(m + 2, bi);               // buffer read at m-1, reads done
        }
        const char* bA = smem + ci * 20480;
        const char* bW = bA + 4096;
#pragma unroll
        for (int khi = 0; khi < 2; ++khi) {
            bf16x8 bfr[2];
#pragma unroll
            for (int ni = 0; ni < 2; ++ni) {
                const int wrow = g * 32 + ni * 16 + l15;
                const int j = (khi * 4 + q) ^ (wrow & 7);
                bfr[ni] = *(const bf16x8*)(bW + wrow * 128 + j * 16);
            }
            const int row = mh * 16 + l15;
            const int j = (khi * 4 + q) ^ (row & 7);
            const bf16x8 av = *(const bf16x8*)(bA + row * 128 + j * 16);
            acc[0] = MFMA_BF16(av, bfr[0], acc[0], 0, 0, 0);
            acc[1] = MFMA_BF16(av, bfr[1], acc[1], 0, 0, 0);
        }
        ++ci; if (ci == 3) ci = 0;
    }

    __syncthreads();
    // eg[g][b_local][u_local], stride 33 ; C/D: row=q*4+r, col=l15 [m89]
#pragma unroll
    for (int ni = 0; ni < 2; ++ni)
#pragma unroll
        for (int r = 0; r < 4; ++r)
            eg[(g * 32 + mh * 16 + q * 4 + r) * 33 + ni * 16 + l15] = acc[ni][r];
    __syncthreads();

    // fused pointwise cell update (scalars prefetched at kernel start)
#pragma unroll
    for (int jj = 0; jj < 2; ++jj) {
        const int bl = bq_e * 2 + jj;
        const int b  = b0 + bl;
        float gv[4];
#pragma unroll
        for (int g4 = 0; g4 < 4; ++g4) gv[g4] = eg[(g4 * 32 + bl) * 33 + u_e] + bs[g4];
        const float x0 = r_x[jj * 2 + 0];
        const float x1 = r_x[jj * 2 + 1];
#pragma unroll
        for (int g4 = 0; g4 < 4; ++g4) gv[g4] += x0 * wx0[g4] + x1 * wx1[g4];
        const float iv = sigf(gv[0]);
        const float fv = sigf(gv[1]);
        const float gg = tanhf(gv[2]);
        const float ov = sigf(gv[3]);
        const size_t idx = (size_t)b * NH + ug_e;
        const float cn = fv * cpre[jj] + iv * gg;
        c[idx] = cn;
        hnext[idx] = f2b(ov * tanhf(cn));
    }
}

// ---------------------------------------------------------------------------
// LSTM2: R9-verified kernel + R14 delta (2) scalar prefetch (npass=2).
// ---------------------------------------------------------------------------
__global__ __launch_bounds__(512, 4) void lstm_mfma32(
    const u16* __restrict__ A0, const u16* __restrict__ W0,
    const u16* __restrict__ A1, const u16* __restrict__ W1,
    const float* __restrict__ bsum,
    float* __restrict__ c, u16* __restrict__ hnext,
    const int npass)
{
    __shared__ __align__(16) char smem[61440];
    float* eg = (float*)smem;

    const int tid  = threadIdx.x;
    const int lane = tid & 63;
    const int wv   = tid >> 6;
    const int g    = wv & 3;
    const int mh   = wv >> 2;
    const int l15  = lane & 15;
    const int q    = lane >> 4;
    const int bx   = blockIdx.x;
    const int ut   = (bx & 7) * 2 + ((bx >> 3) & 1);
    const int grp  = bx >> 4;
    const int b0   = grp * 32;
    const int u0   = ut * 32;

    int goffW0, goffW1, goffA = 0;
    {
        const int c0 = (wv * 2) * 64 + lane;
        const int w0r = c0 >> 3;
        goffW0 = ((w0r >> 5) * NH + u0 + (w0r & 31)) * NH + (((c0 & 7) ^ (w0r & 7)) * 8);
        const int c1i = (wv * 2 + 1) * 64 + lane;
        const int w1r = c1i >> 3;
        goffW1 = ((w1r >> 5) * NH + u0 + (w1r & 31)) * NH + (((c1i & 7) ^ (w1r & 7)) * 8);
        if (wv < 4) {
            const int ca = wv * 64 + lane;
            const int ar = ca >> 3;
            goffA = (b0 + ar) * NH + (((ca & 7) ^ (ar & 7)) * 8);
        }
    }

    // early scalar prefetch (retires alongside macro-0's loads)
    const int u_e  = tid & 31;
    const int bq_e = tid >> 5;
    const int ug_e = u0 + u_e;
    float bs[4], cpre[2];
#pragma unroll
    for (int g4 = 0; g4 < 4; ++g4) bs[g4] = bsum[g4 * NH + ug_e];
    cpre[0] = c[(size_t)(b0 + bq_e * 2 + 0) * NH + ug_e];
    cpre[1] = c[(size_t)(b0 + bq_e * 2 + 1) * NH + ug_e];

    f32x4 acc[2];
    acc[0] = (f32x4){0.f, 0.f, 0.f, 0.f};
    acc[1] = (f32x4){0.f, 0.f, 0.f, 0.f};

    const int M = npass * 8;

    auto issue = [&](int m, int bi) {
        const u16* __restrict__ Ap = (m < 8) ? A0 : A1;
        const u16* __restrict__ Wp = (m < 8) ? W0 : W1;
        const int k0 = (m & 7) * 64;
        char* base = smem + bi * 20480;
        async_cp16((const void*)(Wp + goffW0 + k0),
                   (void*)(base + 4096 + (wv * 2) * 1024));
        async_cp16((const void*)(Wp + goffW1 + k0),
                   (void*)(base + 4096 + (wv * 2 + 1) * 1024));
        if (wv < 4)
            async_cp16((const void*)(Ap + goffA + k0),
                       (void*)(base + wv * 1024));
    };

    issue(0, 0);
    if (M > 1) issue(1, 1);
    int ci = 0;
    for (int m = 0; m < M; ++m) {
        if (m + 1 < M) {
            if (wv < 4) asm volatile("s_waitcnt vmcnt(3)" ::: "memory");
            else        asm volatile("s_waitcnt vmcnt(2)" ::: "memory");
        } else {
            asm volatile("s_waitcnt vmcnt(0)" ::: "memory");
        }
        __builtin_amdgcn_s_barrier();
        if (m + 2 < M) {
            int bi = ci + 2; if (bi >= 3) bi -= 3;
            issue(m + 2, bi);
        }
        const char* bA = smem + ci * 20480;
        const char* bW = bA + 4096;
#pragma unroll
        for (int khi = 0; khi < 2; ++khi) {
            bf16x8 bfr[2];
#pragma unroll
            for (int ni = 0; ni < 2; ++ni) {
                const int wrow = g * 32 + ni * 16 + l15;
                const int j = (khi * 4 + q) ^ (wrow & 7);
                bfr[ni] = *(const bf16x8*)(bW + wrow * 128 + j * 16);
            }
            const int row = mh * 16 + l15;
            const int j = (khi * 4 + q) ^ (row & 7);
            const bf16x8 av = *(const bf16x8*)(bA + row * 128 + j * 16);
            acc[0] = MFMA_BF16(av, bfr[0], acc[0], 0, 0, 0);
            acc[1] = MFMA_BF16(av, bfr[1], acc[1], 0, 0, 0);
        }
        ++ci; if (ci == 3) ci = 0;
    }

    __syncthreads();
#pragma unroll
    for (int ni = 0; ni < 2; ++ni)
#pragma unroll
        for (int r = 0; r < 4; ++r)
            eg[(g * 32 + mh * 16 + q * 4 + r) * 33 + ni * 16 + l15] = acc[ni][r];
    __syncthreads();

#pragma unroll
    for (int jj = 0; jj < 2; ++jj) {
        const int bl = bq_e * 2 + jj;
        const int b  = b0 + bl;
        float gv[4];
#pragma unroll
        for (int g4 = 0; g4 < 4; ++g4) gv[g4] = eg[(g4 * 32 + bl) * 33 + u_e] + bs[g4];
        const float iv = sigf(gv[0]);
        const float fv = sigf(gv[1]);
        const float gg = tanhf(gv[2]);
        const float ov = sigf(gv[3]);
        const size_t idx = (size_t)b * NH + ug_e;
        const float cn = fv * cpre[jj] + iv * gg;
        c[idx] = cn;
        hnext[idx] = f2b(ov * tanhf(cn));
    }
}

// ---------------------------------------------------------------------------
extern "C" void kernel_launch(void* const* d_in, const int* in_sizes, int n_in,
                              void* d_out, int out_size, void* d_ws, size_t ws_size,
                              hipStream_t stream)
{
    const float* zp   = (const float*)d_in[0];
    const float* zsk  = (const float*)d_in[1];
    const float* zst  = (const float*)d_in[2];
    const float* Wp   = (const float*)d_in[3];
    const float* bp   = (const float*)d_in[4];
    const float* Wih1 = (const float*)d_in[5];
    const float* Whh1 = (const float*)d_in[6];
    const float* bih1 = (const float*)d_in[7];
    const float* bhh1 = (const float*)d_in[8];
    const float* Wih2 = (const float*)d_in[9];
    const float* Whh2 = (const float*)d_in[10];
    const float* bih2 = (const float*)d_in[11];
    const float* bhh2 = (const float*)d_in[12];
    const float* Wo1  = (const float*)d_in[13];
    const float* bo1  = (const float*)d_in[14];
    const float* Wo2  = (const float*)d_in[15];
    const float* bo2  = (const float*)d_in[16];

    const size_t BH = (size_t)NB * NH;          // 524288
    u16*   h1a   = (u16*)d_ws;
    u16*   h1b   = h1a + BH;
    u16*   h2a   = h1b + BH;
    u16*   h2b   = h2a + BH;
    float* c1    = (float*)(h2b + BH);
    float* c2    = c1 + BH;
    float* bs1   = c2 + BH;                     // 2048
    float* bs2   = bs1 + 2048;                  // 2048
    u16*   Wo1b  = (u16*)(bs2 + 2048);          // 131072 u16 (row-major bf16)
    u16*   Whh1b = Wo1b + 131072;               // 1048576 each
    u16*   Wih2b = Whh1b + 1048576;
    u16*   Whh2b = Wih2b + 1048576;
    // total ~14.3 MB of d_ws

    convert3<<<(2048 * 512) / 256, 256, 0, stream>>>(Whh1, Wih2, Whh2, Whh1b, Wih2b, Whh2b);
    convw1<<<(256 * 512) / 256, 256, 0, stream>>>(Wo1, Wo1b);
    bsum_k<<<2048 / 256, 256, 0, stream>>>(bih1, bhh1, bih2, bhh2, bs1, bs2);
    init_kernel<<<NB / 4, 256, 0, stream>>>(zp, zsk, zst, Wp, bp, h1a, c1, h2a, c2);

    u16* h1c = h1a; u16* h1n = h1b;
    u16* h2c = h2a; u16* h2n = h2b;
    float* outp = (float*)d_out;
    for (int t = 0; t < NT; ++t) {
        fused_out_lstm1<<<512, 512, 0, stream>>>(
            (t == 0) ? (const u16*)0 : h2c, h1c, Whh1b, bs1, Wih1,
            Wo1b, bo1, Wo2, bo2, outp, c1, h1n, t, 1);
        lstm_mfma32<<<512, 512, 0, stream>>>(h1n, Wih2b, h2c, Whh2b,
                                             bs2, c2, h2n, 2);
        u16* tmp = h1c; h1c = h1n; h1n = tmp;
        tmp = h2c; h2c = h2n; h2n = tmp;
    }
    // final out for t = NT-1 (h2c holds h2(NT-1) after the last swap)
    fused_out_lstm1<<<512, 512, 0, stream>>>(
        h2c, h1c, Whh1b, bs1, Wih1,
        Wo1b, bo1, Wo2, bo2, outp, c1, h1n, NT, 0);
}